// Round 10
// baseline (15.523 us; speedup 1.0000x reference)
//
#include <hip/hip_runtime.h>
#include <math.h>

#define BLOCK 256
#define TPT 2   // tokens per thread; block covers 512 tokens = 1024 float4 slots

typedef float v4f __attribute__((ext_vector_type(4)));

// Even/odd-parity partial sums monoid for type-2 roots. E and O are sums of
// POSITIVE partial weight-products of actual parity classes — every
// intermediate is bounded by the softmax denominator (numerically safe).
// (The Π(g±h) product shortcut is NOT safe: it mixes in odd-parity phantom
// patterns that can exceed the denominator by ~2^40 and cancel destructively —
// R8's absmax=1.02 failure.)
struct EO { float E, O; };
__device__ __forceinline__ EO mergeEO(EO a, EO b) {
    EO r;
    r.E = fmaf(a.E, b.E, a.O * b.O);
    r.O = fmaf(a.E, b.O, a.O * b.E);
    return r;
}

// weights = softmax(20 * x.r) over 240 unit-norm E8 roots, closed form (O(8)):
//  Type-1 (112): rank-1 factorization A=u+v, B=u-v, u=s*g^2, v=s*h^2
//  Type-2 (128): even-parity monoid over (g,h)
//  g/h = exp2(+-K2*x_j - C/8), s = exp2(-C/4), C = (20/ln2)*|x| (all exps <= 0).
__device__ __forceinline__ void e8q_token(const float xs[8], float o[8]) {
    float n2 = 0.0f;
#pragma unroll
    for (int j = 0; j < 8; ++j) n2 = fmaf(xs[j], xs[j], n2);
    const float xn = __builtin_amdgcn_sqrtf(n2);

    const float K2 = 10.201358186637847f;       // (20/ln2)/(2*sqrt(2))
    const float C  = 28.853900817779268f * xn;  // (20/ln2)*|x|
    const float Ce = 0.125f * C;
    const float s  = __builtin_amdgcn_exp2f(-0.25f * C);

    float A[8], B[8], g[8], h[8];
#pragma unroll
    for (int j = 0; j < 8; ++j) {
        g[j] = __builtin_amdgcn_exp2f(fmaf(K2, xs[j], -Ce));
        h[j] = __builtin_amdgcn_exp2f(fmaf(-K2, xs[j], -Ce));
        float a = g[j] * g[j];
        float b = h[j] * h[j];
        float sa = s * a;                // u_j
        A[j] = fmaf(s, b, sa);           // u + v
        B[j] = fmaf(-s, b, sa);          // u - v
    }

    // Suffix arrays; prefixes walked incrementally in the final loop.
    float sufA[8];
    sufA[7] = A[7];
#pragma unroll
    for (int j = 6; j >= 0; --j) sufA[j] = sufA[j + 1] + A[j];

    float s1 = 0.0f;   // sum_{i<j} A_i A_j (all-positive adds)
#pragma unroll
    for (int j = 0; j < 7; ++j) s1 = fmaf(A[j], sufA[j + 1], s1);

    EO suf[8];
    suf[7] = {g[7], h[7]};
#pragma unroll
    for (int j = 6; j >= 1; --j) suf[j] = mergeEO({g[j], h[j]}, suf[j + 1]);

    const float s2 = mergeEO({g[0], h[0]}, suf[1]).E;

    const float inv = __builtin_amdgcn_rcpf(s1 + s2);
    const float c1 = 0.70710678118654752f * inv;   // 1/sqrt2
    const float c2 = 0.35355339059327376f * inv;   // 1/(2*sqrt2)

    float preA = 0.0f;
    EO preEO;
#pragma unroll
    for (int j = 0; j < 8; ++j) {
        float EA;
        EO ex;
        if (j == 0)      { EA = sufA[1];          ex = suf[1]; }
        else if (j == 7) { EA = preA;             ex = preEO; }
        else             { EA = preA + sufA[j+1]; ex = mergeEO(preEO, suf[j+1]); }
        float t2 = fmaf(g[j], ex.E, -(h[j] * ex.O));
        o[j] = fmaf(c1 * B[j], EA, c2 * t2);
        if (j == 0) { preA = A[0]; preEO = {g[0], h[0]}; }
        else        { preA += A[j]; preEO = mergeEO(preEO, {g[j], h[j]}); }
    }
}

// Wave-local split-parity staging on BOTH sides: every global load/store
// instruction is lane-dense (1KB contiguous per wave), and because each wave
// only touches its own LDS region there are NO __syncthreads — same-wave
// ds ordering (compiler lgkmcnt) is sufficient. This fixes R7's mistake
// (dense loads are kept, the global barrier is not).
__global__ __launch_bounds__(BLOCK, 4) void e8q_kernel(const float* __restrict__ x,
                                                       float* __restrict__ out) {
    __shared__ v4f inA[4][64 * TPT];
    __shared__ v4f inB[4][64 * TPT];
    __shared__ v4f outA[4][64 * TPT];
    __shared__ v4f outB[4][64 * TPT];

    const int tid = threadIdx.x;
    const int w = tid >> 6;      // wave id
    const int l = tid & 63;      // lane id
    const size_t T0 = (size_t)blockIdx.x * (BLOCK * TPT);
    const v4f* xv = (const v4f*)x + T0 * 2;
    v4f* ov = (v4f*)out + T0 * 2;

    // Wave w owns global v4f slots [128w,128w+128) and [512+128w, ...+128).
    // Local slot s (0..255): s<128 -> gslot 128w+s ; s>=128 -> 512+128w+(s-128).

    // Phase 1: dense global loads, all issued up front (MLP).
    v4f ld[2 * TPT];
#pragma unroll
    for (int j = 0; j < 2; ++j) ld[j] = xv[128 * w + j * 64 + l];
#pragma unroll
    for (int j = 0; j < 2; ++j) ld[2 + j] = xv[512 + 128 * w + j * 64 + l];

    // Phase 2: scatter to parity-split wave-local LDS.
#pragma unroll
    for (int j = 0; j < 2 * TPT; ++j) {
        const int s = j * 64 + l;
        if (s & 1) inB[w][s >> 1] = ld[j];
        else       inA[w][s >> 1] = ld[j];
    }

    // Phase 3: token-major readback + compute + stage results.
    // Local token tl: tl<64 -> global token T0+64w+tl ; tl>=64 -> T0+256+64w+(tl-64).
#pragma unroll
    for (int p = 0; p < TPT; ++p) {
        const int tl = p * 64 + l;
        v4f a = inA[w][tl];
        v4f b = inB[w][tl];
        float xs[8] = {a.x, a.y, a.z, a.w, b.x, b.y, b.z, b.w};
        float o[8];
        e8q_token(xs, o);
        outA[w][tl] = (v4f){o[0], o[1], o[2], o[3]};
        outB[w][tl] = (v4f){o[4], o[5], o[6], o[7]};
    }

    // Phase 4: dense flush (same slot mapping as the loads).
#pragma unroll
    for (int j = 0; j < 2 * TPT; ++j) {
        const int s = j * 64 + l;
        v4f val = (s & 1) ? outB[w][s >> 1] : outA[w][s >> 1];
        const int gslot = (j < 2) ? (128 * w + j * 64 + l)
                                  : (512 + 128 * w + (j - 2) * 64 + l);
        __builtin_nontemporal_store(val, ov + gslot);
    }
}

extern "C" void kernel_launch(void* const* d_in, const int* in_sizes, int n_in,
                              void* d_out, int out_size, void* d_ws, size_t ws_size,
                              hipStream_t stream) {
    const float* x = (const float*)d_in[0];
    float* out = (float*)d_out;

    const int tokens = in_sizes[0] / 8;        // 1,048,576
    const int grid = tokens / (BLOCK * TPT);   // 2048

    e8q_kernel<<<grid, BLOCK, 0, stream>>>(x, out);
}

// Round 11
// 14.866 us; speedup vs baseline: 1.0442x; 1.0442x over previous
//
#include <hip/hip_runtime.h>
#include <math.h>

#define BLOCK 256
#define TPT 2   // tokens per thread; wave owns two contiguous 2KB output ranges

typedef float v4f __attribute__((ext_vector_type(4)));

// Even/odd-parity partial sums monoid for type-2 roots. E and O are sums of
// POSITIVE partial weight-products of actual parity classes — every
// intermediate is bounded by the softmax denominator (numerically safe).
// (The Π(g±h) product shortcut is NOT safe — R8's absmax=1.02 failure.)
struct EO { float E, O; };
__device__ __forceinline__ EO mergeEO(EO a, EO b) {
    EO r;
    r.E = fmaf(a.E, b.E, a.O * b.O);
    r.O = fmaf(a.E, b.O, a.O * b.E);
    return r;
}

// weights = softmax(20 * x.r) over 240 unit-norm E8 roots, closed form (O(8)):
//  Type-1 (112): rank-1 factorization A=u+v, B=u-v, u=s*g^2, v=s*h^2
//  Type-2 (128): even-parity monoid over (g,h)
//  g/h = exp2(+-K2*x_j - C/8), s = exp2(-C/4), C = (20/ln2)*|x| (all exps <= 0).
__device__ __forceinline__ void e8q_token(const float xs[8], float o[8]) {
    float n2 = 0.0f;
#pragma unroll
    for (int j = 0; j < 8; ++j) n2 = fmaf(xs[j], xs[j], n2);
    const float xn = __builtin_amdgcn_sqrtf(n2);

    const float K2 = 10.201358186637847f;       // (20/ln2)/(2*sqrt(2))
    const float C  = 28.853900817779268f * xn;  // (20/ln2)*|x|
    const float Ce = 0.125f * C;
    const float s  = __builtin_amdgcn_exp2f(-0.25f * C);

    float A[8], B[8], g[8], h[8];
#pragma unroll
    for (int j = 0; j < 8; ++j) {
        g[j] = __builtin_amdgcn_exp2f(fmaf(K2, xs[j], -Ce));
        h[j] = __builtin_amdgcn_exp2f(fmaf(-K2, xs[j], -Ce));
        float a = g[j] * g[j];
        float b = h[j] * h[j];
        float sa = s * a;                // u_j
        A[j] = fmaf(s, b, sa);           // u + v
        B[j] = fmaf(-s, b, sa);          // u - v
    }

    // Suffix arrays; prefixes walked incrementally in the final loop
    // (saves ~30 live VGPRs vs materializing pre[]/ex[]).
    float sufA[8];
    sufA[7] = A[7];
#pragma unroll
    for (int j = 6; j >= 0; --j) sufA[j] = sufA[j + 1] + A[j];

    float s1 = 0.0f;   // sum_{i<j} A_i A_j (all-positive adds)
#pragma unroll
    for (int j = 0; j < 7; ++j) s1 = fmaf(A[j], sufA[j + 1], s1);

    EO suf[8];
    suf[7] = {g[7], h[7]};
#pragma unroll
    for (int j = 6; j >= 1; --j) suf[j] = mergeEO({g[j], h[j]}, suf[j + 1]);

    const float s2 = mergeEO({g[0], h[0]}, suf[1]).E;

    const float inv = __builtin_amdgcn_rcpf(s1 + s2);
    const float c1 = 0.70710678118654752f * inv;   // 1/sqrt2
    const float c2 = 0.35355339059327376f * inv;   // 1/(2*sqrt2)

    float preA = 0.0f;
    EO preEO;
#pragma unroll
    for (int j = 0; j < 8; ++j) {
        float EA;
        EO ex;
        if (j == 0)      { EA = sufA[1];            ex = suf[1]; }
        else if (j == 7) { EA = preA;               ex = preEO; }
        else             { EA = preA + sufA[j + 1]; ex = mergeEO(preEO, suf[j + 1]); }
        float t2 = fmaf(g[j], ex.E, -(h[j] * ex.O));
        o[j] = fmaf(c1 * B[j], EA, c2 * t2);
        if (j == 0) { preA = A[0];  preEO = {g[0], h[0]}; }
        else        { preA += A[j]; preEO = mergeEO(preEO, {g[j], h[j]}); }
    }
}

// R6's structure with the block barrier removed:
//  - input: strided per-thread dwordx4 loads (L1 merges half-line pairs; each
//    thread computes as soon as its OWN loads land — no coupling),
//  - output: wave-local parity-split LDS staging + dense nontemporal flush
//    (every store instruction covers a contiguous 1KB per wave). No
//    __syncthreads anywhere: waves only read LDS they themselves wrote.
__global__ __launch_bounds__(BLOCK, 4) void e8q_kernel(const float* __restrict__ x,
                                                       float* __restrict__ out) {
    __shared__ v4f outA[4][64 * TPT];
    __shared__ v4f outB[4][64 * TPT];

    const int tid = threadIdx.x;
    const int w = tid >> 6;      // wave id
    const int l = tid & 63;      // lane id
    const size_t T0 = (size_t)blockIdx.x * (BLOCK * TPT);

    // Issue all loads up front (4x dwordx4) for MLP.
    v4f xv[TPT][2];
#pragma unroll
    for (int p = 0; p < TPT; ++p) {
        const v4f* xp = (const v4f*)(x + (T0 + tid + (size_t)p * BLOCK) * 8);
        xv[p][0] = xp[0];
        xv[p][1] = xp[1];
    }

    // Compute + stage. Wave w's token for pass p is T0 + p*BLOCK + 64w + l;
    // local token index tl = 64p + l in the wave's private region.
#pragma unroll
    for (int p = 0; p < TPT; ++p) {
        float xs[8] = {xv[p][0].x, xv[p][0].y, xv[p][0].z, xv[p][0].w,
                       xv[p][1].x, xv[p][1].y, xv[p][1].z, xv[p][1].w};
        float o[8];
        e8q_token(xs, o);
        const int tl = p * 64 + l;
        outA[w][tl] = (v4f){o[0], o[1], o[2], o[3]};
        outB[w][tl] = (v4f){o[4], o[5], o[6], o[7]};
    }

    // Dense flush, wave-local (no barrier). Wave w's tokens occupy v4f-slot
    // ranges [128w, 128w+128) and [512+128w, 512+128w+128) within the block.
    v4f* ov = (v4f*)out + T0 * 2;
#pragma unroll
    for (int j = 0; j < 2 * TPT; ++j) {
        const int s = j * 64 + l;                       // wave-local slot 0..255
        v4f val = (s & 1) ? outB[w][s >> 1] : outA[w][s >> 1];
        const int gslot = (j < 2) ? (128 * w + j * 64 + l)
                                  : (512 + 128 * w + (j - 2) * 64 + l);
        __builtin_nontemporal_store(val, ov + gslot);
    }
}

extern "C" void kernel_launch(void* const* d_in, const int* in_sizes, int n_in,
                              void* d_out, int out_size, void* d_ws, size_t ws_size,
                              hipStream_t stream) {
    const float* x = (const float*)d_in[0];
    float* out = (float*)d_out;

    const int tokens = in_sizes[0] / 8;        // 1,048,576
    const int grid = tokens / (BLOCK * TPT);   // 2048

    e8q_kernel<<<grid, BLOCK, 0, stream>>>(x, out);
}

// Round 12
// 13.690 us; speedup vs baseline: 1.1339x; 1.0859x over previous
//
#include <hip/hip_runtime.h>
#include <math.h>

#define BLOCK 256
#define TPT 2   // tokens per thread

typedef float v4f __attribute__((ext_vector_type(4)));

// Even/odd-parity partial sums monoid for type-2 roots. E and O are sums of
// POSITIVE partial weight-products of actual parity classes — every
// intermediate is bounded by the softmax denominator (numerically safe).
// (The Π(g±h) product shortcut is NOT safe — R8's absmax=1.02 failure.)
struct EO { float E, O; };
__device__ __forceinline__ EO mergeEO(EO a, EO b) {
    EO r;
    r.E = fmaf(a.E, b.E, a.O * b.O);
    r.O = fmaf(a.E, b.O, a.O * b.E);
    return r;
}

// weights = softmax(20 * x.r) over 240 unit-norm E8 roots, closed form (O(8)):
//  Type-1 (112): rank-1 factorization A=u+v, B=u-v, u=s*g^2, v=s*h^2
//  Type-2 (128): even-parity monoid over (g,h)
//  g/h = exp2(+-K2*x_j - C/8), s = exp2(-C/4), C = (20/ln2)*|x| (all exps <= 0).
// NOTE: materialized pre[]/suf[]/ex[] arrays on purpose (R6 version): the
// pre- and suf-chains run in parallel and the 6 ex-merges are independent —
// better per-thread ILP than the fused running-prefix walk (R9/R11, ~1us slower).
__device__ __forceinline__ void e8q_token(const float xs[8], float o[8]) {
    float n2 = 0.0f;
#pragma unroll
    for (int j = 0; j < 8; ++j) n2 = fmaf(xs[j], xs[j], n2);
    const float xn = __builtin_amdgcn_sqrtf(n2);

    const float K2 = 10.201358186637847f;       // (20/ln2)/(2*sqrt(2))
    const float C  = 28.853900817779268f * xn;  // (20/ln2)*|x|
    const float Ce = 0.125f * C;
    const float s  = __builtin_amdgcn_exp2f(-0.25f * C);

    float A[8], B[8], g[8], h[8];
#pragma unroll
    for (int j = 0; j < 8; ++j) {
        g[j] = __builtin_amdgcn_exp2f(fmaf(K2, xs[j], -Ce));
        h[j] = __builtin_amdgcn_exp2f(fmaf(-K2, xs[j], -Ce));
        float a = g[j] * g[j];
        float b = h[j] * h[j];
        float sa = s * a;                // u_j
        A[j] = fmaf(s, b, sa);           // u + v
        B[j] = fmaf(-s, b, sa);          // u - v
    }

    // Type-1: exclude-one sums via prefix+suffix adds (no cancelling subtraction)
    float preA[8], sufA[8];
    preA[0] = A[0];
#pragma unroll
    for (int j = 1; j < 8; ++j) preA[j] = preA[j - 1] + A[j];
    sufA[7] = A[7];
#pragma unroll
    for (int j = 6; j >= 0; --j) sufA[j] = sufA[j + 1] + A[j];

    float EA[8];
    EA[0] = sufA[1];
    EA[7] = preA[6];
#pragma unroll
    for (int j = 1; j < 7; ++j) EA[j] = preA[j - 1] + sufA[j + 1];

    float s1 = 0.0f;   // sum_{i<j} A_i A_j (all 112 type-1 weights)
#pragma unroll
    for (int j = 0; j < 7; ++j) s1 = fmaf(A[j], sufA[j + 1], s1);

    // Type-2: parity monoid prefix/suffix (two parallel chains, independent merges)
    EO pre[8], suf[8];
    pre[0] = {g[0], h[0]};
#pragma unroll
    for (int j = 1; j < 8; ++j) pre[j] = mergeEO(pre[j - 1], {g[j], h[j]});
    suf[7] = {g[7], h[7]};
#pragma unroll
    for (int j = 6; j >= 1; --j) suf[j] = mergeEO({g[j], h[j]}, suf[j + 1]);

    const float s2 = pre[7].E;

    EO ex[8];
    ex[0] = suf[1];
    ex[7] = pre[6];
#pragma unroll
    for (int j = 1; j < 7; ++j) ex[j] = mergeEO(pre[j - 1], suf[j + 1]);

    const float inv = __builtin_amdgcn_rcpf(s1 + s2);
    const float c1 = 0.70710678118654752f * inv;   // 1/sqrt2
    const float c2 = 0.35355339059327376f * inv;   // 1/(2*sqrt2)

#pragma unroll
    for (int j = 0; j < 8; ++j) {
        float t1 = B[j] * EA[j];
        float t2 = fmaf(g[j], ex[j].E, -(h[j] * ex[j].O));
        o[j] = fmaf(c1, t1, c2 * t2);
    }
}

// R6's structure with the block barrier removed:
//  - input: strided per-thread dwordx4 loads, all issued up front (L1 merges
//    half-line pairs; each thread computes as soon as its own loads land),
//  - output: wave-local parity-split LDS staging + dense nontemporal flush
//    (every store instruction covers contiguous 1KB per wave). No
//    __syncthreads: waves only read LDS they themselves wrote.
__global__ __launch_bounds__(BLOCK, 4) void e8q_kernel(const float* __restrict__ x,
                                                       float* __restrict__ out) {
    __shared__ v4f outA[4][64 * TPT];
    __shared__ v4f outB[4][64 * TPT];

    const int tid = threadIdx.x;
    const int w = tid >> 6;      // wave id
    const int l = tid & 63;      // lane id
    const size_t T0 = (size_t)blockIdx.x * (BLOCK * TPT);

    // Issue all loads up front (4x dwordx4) for MLP.
    v4f xv[TPT][2];
#pragma unroll
    for (int p = 0; p < TPT; ++p) {
        const v4f* xp = (const v4f*)(x + (T0 + tid + (size_t)p * BLOCK) * 8);
        xv[p][0] = xp[0];
        xv[p][1] = xp[1];
    }

    // Compute + stage. Pass p, lane l -> block-token p*256 + 64w + l,
    // wave-local token index tl = 64p + l.
#pragma unroll
    for (int p = 0; p < TPT; ++p) {
        float xs[8] = {xv[p][0].x, xv[p][0].y, xv[p][0].z, xv[p][0].w,
                       xv[p][1].x, xv[p][1].y, xv[p][1].z, xv[p][1].w};
        float o[8];
        e8q_token(xs, o);
        const int tl = p * 64 + l;
        outA[w][tl] = (v4f){o[0], o[1], o[2], o[3]};
        outB[w][tl] = (v4f){o[4], o[5], o[6], o[7]};
    }

    // Dense flush, wave-local (no barrier). Wave w's tokens occupy v4f-slot
    // ranges [128w, 128w+128) and [512+128w, 512+128w+128) within the block.
    v4f* ov = (v4f*)out + T0 * 2;
#pragma unroll
    for (int j = 0; j < 2 * TPT; ++j) {
        const int s = j * 64 + l;                       // wave-local slot 0..255
        v4f val = (s & 1) ? outB[w][s >> 1] : outA[w][s >> 1];
        const int gslot = (j < 2) ? (128 * w + j * 64 + l)
                                  : (512 + 128 * w + (j - 2) * 64 + l);
        __builtin_nontemporal_store(val, ov + gslot);
    }
}

extern "C" void kernel_launch(void* const* d_in, const int* in_sizes, int n_in,
                              void* d_out, int out_size, void* d_ws, size_t ws_size,
                              hipStream_t stream) {
    const float* x = (const float*)d_in[0];
    float* out = (float*)d_out;

    const int tokens = in_sizes[0] / 8;        // 1,048,576
    const int grid = tokens / (BLOCK * TPT);   // 2048

    e8q_kernel<<<grid, BLOCK, 0, stream>>>(x, out);
}